// Round 3
// baseline (2111.218 us; speedup 1.0000x reference)
//
#include <hip/hip_runtime.h>
#include <hip/hip_bf16.h>
#include <cstddef>

#define SEQ 2048
#define DM  512
#define DI  1024   // d_inner
#define DR  32     // dt_rank
#define DS  64     // d_state
#define DXZ 2048   // 2*DI

// ---------------- LayerNorm: one block (256 thr) per token ----------------
__global__ void ln_kernel(const float* __restrict__ x, const float* __restrict__ g,
                          const float* __restrict__ b, float* __restrict__ xn) {
    int l = blockIdx.x;
    int t = threadIdx.x;
    __shared__ float red[256];
    float v0 = x[l * DM + t];
    float v1 = x[l * DM + t + 256];
    red[t] = v0 + v1;
    __syncthreads();
    for (int o = 128; o > 0; o >>= 1) { if (t < o) red[t] += red[t + o]; __syncthreads(); }
    float mu = red[0] * (1.f / DM);
    __syncthreads();
    float c0 = v0 - mu, c1 = v1 - mu;
    red[t] = c0 * c0 + c1 * c1;
    __syncthreads();
    for (int o = 128; o > 0; o >>= 1) { if (t < o) red[t] += red[t + o]; __syncthreads(); }
    float rstd = rsqrtf(red[0] * (1.f / DM) + 1e-5f);
    xn[l * DM + t]       = c0 * rstd * g[t]       + b[t];
    xn[l * DM + t + 256] = c1 * rstd * g[t + 256] + b[t + 256];
}

// ---------------- Generic tiled GEMM: C[M,N] = A[M,K] * B[N,K]^T ----------
// 64x64 tile, BK=16, 256 threads, 4x4 microtile.
// EPI: 0 = store f32; 1 = softplus(acc+bias) f32; 2 = acc+residual f32.
template <int EPI>
__global__ void gemm_kernel(const float* __restrict__ A, int lda,
                            const float* __restrict__ B, int ldb,
                            int M, int N, int K,
                            float* __restrict__ out,
                            const float* __restrict__ ep_bias,
                            const float* __restrict__ ep_res, int ldo) {
    __shared__ float As[16][65];
    __shared__ float Bs[16][65];
    int tid = threadIdx.x;
    int tx = tid & 15, ty = tid >> 4;
    int bm = blockIdx.x * 64, bn = blockIdx.y * 64;
    float acc[4][4] = {};
    int kk = tid & 15;   // k within tile
    int rr = tid >> 4;   // row/col slice base

    for (int k0 = 0; k0 < K; k0 += 16) {
#pragma unroll
        for (int i = 0; i < 4; i++) {
            int m = bm + rr + 16 * i;
            As[kk][rr + 16 * i] = (m < M) ? A[(size_t)m * lda + k0 + kk] : 0.f;
        }
#pragma unroll
        for (int i = 0; i < 4; i++) {
            int n = bn + rr + 16 * i;
            Bs[kk][rr + 16 * i] = (n < N) ? B[(size_t)n * ldb + k0 + kk] : 0.f;
        }
        __syncthreads();
#pragma unroll
        for (int k = 0; k < 16; k++) {
            float a[4], bb[4];
#pragma unroll
            for (int i = 0; i < 4; i++) a[i] = As[k][ty * 4 + i];
#pragma unroll
            for (int j = 0; j < 4; j++) bb[j] = Bs[k][tx * 4 + j];
#pragma unroll
            for (int i = 0; i < 4; i++)
#pragma unroll
                for (int j = 0; j < 4; j++)
                    acc[i][j] = fmaf(a[i], bb[j], acc[i][j]);
        }
        __syncthreads();
    }

#pragma unroll
    for (int i = 0; i < 4; i++) {
#pragma unroll
        for (int j = 0; j < 4; j++) {
            int m = bm + ty * 4 + i;
            int n = bn + tx * 4 + j;
            if (m < M && n < N) {
                float v = acc[i][j];
                if (EPI == 1) {
                    v += ep_bias[n];
                    v = (v > 20.f) ? v : __logf(1.f + __expf(v));
                } else if (EPI == 2) {
                    v += ep_res[(size_t)m * ldo + n];
                }
                out[(size_t)m * ldo + n] = v;
            }
        }
    }
}

// ---------------- Causal depthwise conv (width 4) + bias + SiLU -----------
// xi_raw layout: [SEQ][DI]
__global__ void conv_kernel(const float* __restrict__ xi_raw, const float* __restrict__ w,
                            const float* __restrict__ cb, float* __restrict__ xi2) {
    int idx = blockIdx.x * 256 + threadIdx.x;   // SEQ*DI threads
    int e = idx & (DI - 1);
    int l = idx >> 10;
    float acc = cb[e];
#pragma unroll
    for (int j = 0; j < 4; j++) {
        int ls = l - 3 + j;
        if (ls >= 0) acc = fmaf(w[e * 4 + j], xi_raw[(size_t)ls * DI + e], acc);
    }
    float sig = 1.f / (1.f + __expf(-acc));
    xi2[idx] = acc * sig;
}

// ---------------- Selective scan: one wave per channel e, lane = state n --
// zy: z on input, overwritten in-place with gated y (safe: read-before-write
// within the owning wave; no other wave touches [l,e]).
__global__ void scan_kernel(const float* __restrict__ delta, const float* __restrict__ xi2,
                            const float* __restrict__ dbc, float* __restrict__ zy,
                            const float* __restrict__ A_log, const float* __restrict__ Dp) {
    int e = (blockIdx.x << 2) + (threadIdx.x >> 6);  // channel, 0..1023
    int n = threadIdx.x & 63;                        // state,   0..63
    float Ae = -__expf(A_log[e * DS + n]);
    float dp = Dp[e];
    float h = 0.f;
    for (int l = 0; l < SEQ; l++) {
        float d  = delta[l * DI + e];
        float xv = xi2[l * DI + e];
        float zv = zy[(size_t)l * DI + e];
        float Bn = dbc[l * 160 + DR + n];
        float Cn = dbc[l * 160 + DR + DS + n];
        float dA = __expf(d * Ae);
        h = fmaf(dA, h, d * xv * Bn);
        float p = h * Cn;
#pragma unroll
        for (int off = 32; off > 0; off >>= 1) p += __shfl_xor(p, off, 64);
        if (n == 0) {
            float yv = p + dp * xv;
            float sig = 1.f / (1.f + __expf(-zv));
            zy[(size_t)l * DI + e] = yv * (zv * sig);
        }
    }
}

extern "C" void kernel_launch(void* const* d_in, const int* in_sizes, int n_in,
                              void* d_out, int out_size, void* d_ws, size_t ws_size,
                              hipStream_t stream) {
    const float* x      = (const float*)d_in[0];
    const float* ln_g   = (const float*)d_in[1];
    const float* ln_b   = (const float*)d_in[2];
    const float* Win    = (const float*)d_in[3];
    const float* conv_w = (const float*)d_in[4];
    const float* conv_b = (const float*)d_in[5];
    const float* Wx     = (const float*)d_in[6];
    const float* Wdt    = (const float*)d_in[7];
    const float* bdt    = (const float*)d_in[8];
    const float* A_log  = (const float*)d_in[9];
    const float* Dp     = (const float*)d_in[10];
    const float* Wout   = (const float*)d_in[11];
    float* out = (float*)d_out;

    // Workspace: 28 MB total (reused buffers; previous 45 MB layout overflowed
    // ws and corrupted adjacent allocations -> post-timing divergence).
    float* ws   = (float*)d_ws;
    float* bufA = ws;                            // 1,048,576 f: xn, then dbc
    float* bufB = bufA + (size_t)SEQ * DM;       // 2,097,152 f: xi_raw, then delta
    float* bufC = bufB + (size_t)SEQ * DI;       // 2,097,152 f: z, then y (in-place)
    float* bufD = bufC + (size_t)SEQ * DI;       // 2,097,152 f: xi2

    float* xn     = bufA;
    float* xi_raw = bufB;
    float* zy     = bufC;
    float* xi2    = bufD;
    float* dbc    = bufA;   // reuse: xn dead after in-proj
    float* delta  = bufB;   // reuse: xi_raw dead after conv

    // 1. LayerNorm
    ln_kernel<<<SEQ, 256, 0, stream>>>(x, ln_g, ln_b, xn);

    // 2a. xi_raw = xn @ Win[0:DI]^T   (2048 x 1024 x 512)
    gemm_kernel<0><<<dim3(SEQ / 64, DI / 64), 256, 0, stream>>>(
        xn, DM, Win, DM, SEQ, DI, DM, xi_raw, nullptr, nullptr, DI);
    // 2b. z = xn @ Win[DI:2*DI]^T     (2048 x 1024 x 512)
    gemm_kernel<0><<<dim3(SEQ / 64, DI / 64), 256, 0, stream>>>(
        xn, DM, Win + (size_t)DI * DM, DM, SEQ, DI, DM, zy, nullptr, nullptr, DI);

    // 3. conv + SiLU -> xi2
    conv_kernel<<<(SEQ * DI) / 256, 256, 0, stream>>>(xi_raw, conv_w, conv_b, xi2);

    // 4. dbc = xi2 @ Wx^T  (2048 x 160 x 1024)  [overwrites xn region]
    gemm_kernel<0><<<dim3(SEQ / 64, (160 + 63) / 64), 256, 0, stream>>>(
        xi2, DI, Wx, DI, SEQ, 160, DI, dbc, nullptr, nullptr, 160);

    // 5. delta = softplus(dbc[:, :32] @ Wdt^T + bdt)  (2048 x 1024 x 32)
    gemm_kernel<1><<<dim3(SEQ / 64, DI / 64), 256, 0, stream>>>(
        dbc, 160, Wdt, DR, SEQ, DI, DR, delta, bdt, nullptr, DI);

    // 6. selective scan + Dp skip + z-gate -> zy (in-place over z)
    scan_kernel<<<DI / 4, 256, 0, stream>>>(delta, xi2, dbc, zy, A_log, Dp);

    // 7. out = y @ Wout^T + x  (2048 x 512 x 1024)
    gemm_kernel<2><<<dim3(SEQ / 64, DM / 64), 256, 0, stream>>>(
        zy, DI, Wout, DI, SEQ, DM, DI, out, nullptr, x, DM);
}

// Round 4
// 869.193 us; speedup vs baseline: 2.4289x; 2.4289x over previous
//
#include <hip/hip_runtime.h>
#include <hip/hip_bf16.h>
#include <cstddef>

#define SEQ 2048
#define DM  512
#define DI  1024   // d_inner
#define DR  32     // dt_rank
#define DS  64     // d_state
#define NCHUNK 8
#define CHUNK  256 // SEQ / NCHUNK

// ---------------- LayerNorm: one block (256 thr) per token ----------------
__global__ void ln_kernel(const float* __restrict__ x, const float* __restrict__ g,
                          const float* __restrict__ b, float* __restrict__ xn) {
    int l = blockIdx.x;
    int t = threadIdx.x;
    __shared__ float red[256];
    float v0 = x[l * DM + t];
    float v1 = x[l * DM + t + 256];
    red[t] = v0 + v1;
    __syncthreads();
    for (int o = 128; o > 0; o >>= 1) { if (t < o) red[t] += red[t + o]; __syncthreads(); }
    float mu = red[0] * (1.f / DM);
    __syncthreads();
    float c0 = v0 - mu, c1 = v1 - mu;
    red[t] = c0 * c0 + c1 * c1;
    __syncthreads();
    for (int o = 128; o > 0; o >>= 1) { if (t < o) red[t] += red[t + o]; __syncthreads(); }
    float rstd = rsqrtf(red[0] * (1.f / DM) + 1e-5f);
    xn[l * DM + t]       = c0 * rstd * g[t]       + b[t];
    xn[l * DM + t + 256] = c1 * rstd * g[t + 256] + b[t + 256];
}

// ---------------- Generic tiled GEMM: C[M,N] = A[M,K] * B[N,K]^T ----------
// 64x64 tile, BK=16, 256 threads, 4x4 microtile.
// EPI: 0 = store f32; 1 = softplus(acc+bias) f32; 2 = acc+residual f32.
template <int EPI>
__global__ void gemm_kernel(const float* __restrict__ A, int lda,
                            const float* __restrict__ B, int ldb,
                            int M, int N, int K,
                            float* __restrict__ out,
                            const float* __restrict__ ep_bias,
                            const float* __restrict__ ep_res, int ldo) {
    __shared__ float As[16][65];
    __shared__ float Bs[16][65];
    int tid = threadIdx.x;
    int tx = tid & 15, ty = tid >> 4;
    int bm = blockIdx.x * 64, bn = blockIdx.y * 64;
    float acc[4][4] = {};
    int kk = tid & 15;
    int rr = tid >> 4;

    for (int k0 = 0; k0 < K; k0 += 16) {
#pragma unroll
        for (int i = 0; i < 4; i++) {
            int m = bm + rr + 16 * i;
            As[kk][rr + 16 * i] = (m < M) ? A[(size_t)m * lda + k0 + kk] : 0.f;
        }
#pragma unroll
        for (int i = 0; i < 4; i++) {
            int n = bn + rr + 16 * i;
            Bs[kk][rr + 16 * i] = (n < N) ? B[(size_t)n * ldb + k0 + kk] : 0.f;
        }
        __syncthreads();
#pragma unroll
        for (int k = 0; k < 16; k++) {
            float a[4], bb[4];
#pragma unroll
            for (int i = 0; i < 4; i++) a[i] = As[k][ty * 4 + i];
#pragma unroll
            for (int j = 0; j < 4; j++) bb[j] = Bs[k][tx * 4 + j];
#pragma unroll
            for (int i = 0; i < 4; i++)
#pragma unroll
                for (int j = 0; j < 4; j++)
                    acc[i][j] = fmaf(a[i], bb[j], acc[i][j]);
        }
        __syncthreads();
    }

#pragma unroll
    for (int i = 0; i < 4; i++) {
#pragma unroll
        for (int j = 0; j < 4; j++) {
            int m = bm + ty * 4 + i;
            int n = bn + tx * 4 + j;
            if (m < M && n < N) {
                float v = acc[i][j];
                if (EPI == 1) {
                    v += ep_bias[n];
                    v = (v > 20.f) ? v : __logf(1.f + __expf(v));
                } else if (EPI == 2) {
                    v += ep_res[(size_t)m * ldo + n];
                }
                out[(size_t)m * ldo + n] = v;
            }
        }
    }
}

// ---------------- Causal depthwise conv (width 4) + bias + SiLU -----------
__global__ void conv_kernel(const float* __restrict__ xi_raw, const float* __restrict__ w,
                            const float* __restrict__ cb, float* __restrict__ xi2) {
    int idx = blockIdx.x * 256 + threadIdx.x;
    int e = idx & (DI - 1);
    int l = idx >> 10;
    float acc = cb[e];
#pragma unroll
    for (int j = 0; j < 4; j++) {
        int ls = l - 3 + j;
        if (ls >= 0) acc = fmaf(w[e * 4 + j], xi_raw[(size_t)ls * DI + e], acc);
    }
    float sig = 1.f / (1.f + __expf(-acc));
    xi2[idx] = acc * sig;
}

// ---------------- Chunked selective scan ----------------------------------
// Wave (e, c), lane = state n. Pass A: local scan (h_in = 0), emit
// P = prod(dA) and h_end per state. No stores inside the loop -> pipelined.
__global__ void scan_passA(const float* __restrict__ delta, const float* __restrict__ xi2,
                           const float* __restrict__ dbc, const float* __restrict__ A_log,
                           float* __restrict__ P, float* __restrict__ hend) {
    int wid = blockIdx.x * 4 + (threadIdx.x >> 6);
    int e = wid & (DI - 1);
    int c = wid >> 10;
    int n = threadIdx.x & 63;
    float Ae = -__expf(A_log[e * DS + n]);
    float h = 0.f, Pn = 1.f;
    int l0 = c * CHUNK;
    for (int l = l0; l < l0 + CHUNK; l++) {
        float d  = delta[l * DI + e];
        float xv = xi2[l * DI + e];
        float Bn = dbc[l * 160 + DR + n];
        float dA = __expf(d * Ae);
        h = fmaf(dA, h, d * xv * Bn);
        Pn *= dA;
    }
    int idx = (c * DI + e) * DS + n;
    P[idx] = Pn;
    hend[idx] = h;
}

// Carry: h_in[c+1] = P[c]*h_in[c] + hend[c]; h_in written in-place over P.
__global__ void scan_carry(float* __restrict__ P, const float* __restrict__ hend) {
    int e = blockIdx.x * 4 + (threadIdx.x >> 6);
    int n = threadIdx.x & 63;
    float h = 0.f;
    for (int c = 0; c < NCHUNK; c++) {
        int idx = (c * DI + e) * DS + n;
        float p  = P[idx];
        float he = hend[idx];
        P[idx] = h;            // h_in for chunk c
        h = fmaf(p, h, he);
    }
}

// Pass B: re-scan from exact h_in, reduce y, Dp-skip + z-gate, store into zy.
__global__ void scan_passB(const float* __restrict__ delta, const float* __restrict__ xi2,
                           const float* __restrict__ dbc, float* __restrict__ zy,
                           const float* __restrict__ A_log, const float* __restrict__ Dp,
                           const float* __restrict__ hin) {
    int wid = blockIdx.x * 4 + (threadIdx.x >> 6);
    int e = wid & (DI - 1);
    int c = wid >> 10;
    int n = threadIdx.x & 63;
    float Ae = -__expf(A_log[e * DS + n]);
    float dp = Dp[e];
    float h = hin[(c * DI + e) * DS + n];
    int l0 = c * CHUNK;
    for (int l = l0; l < l0 + CHUNK; l++) {
        float d  = delta[l * DI + e];
        float xv = xi2[l * DI + e];
        float zv = zy[(size_t)l * DI + e];
        float Bn = dbc[l * 160 + DR + n];
        float Cn = dbc[l * 160 + DR + DS + n];
        float dA = __expf(d * Ae);
        h = fmaf(dA, h, d * xv * Bn);
        float p = h * Cn;
#pragma unroll
        for (int off = 32; off > 0; off >>= 1) p += __shfl_xor(p, off, 64);
        if (n == 0) {
            float yv = p + dp * xv;
            float sig = 1.f / (1.f + __expf(-zv));
            zy[(size_t)l * DI + e] = yv * (zv * sig);
        }
    }
}

extern "C" void kernel_launch(void* const* d_in, const int* in_sizes, int n_in,
                              void* d_out, int out_size, void* d_ws, size_t ws_size,
                              hipStream_t stream) {
    const float* x      = (const float*)d_in[0];
    const float* ln_g   = (const float*)d_in[1];
    const float* ln_b   = (const float*)d_in[2];
    const float* Win    = (const float*)d_in[3];
    const float* conv_w = (const float*)d_in[4];
    const float* conv_b = (const float*)d_in[5];
    const float* Wx     = (const float*)d_in[6];
    const float* Wdt    = (const float*)d_in[7];
    const float* bdt    = (const float*)d_in[8];
    const float* A_log  = (const float*)d_in[9];
    const float* Dp     = (const float*)d_in[10];
    const float* Wout   = (const float*)d_in[11];
    float* out = (float*)d_out;

    // Workspace: 30 MB. bufA holds xn, then dbc (1.31 MB) + P (2 MB) in its tail.
    float* ws   = (float*)d_ws;
    float* bufA = ws;                            // 1,048,576 f
    float* bufB = bufA + (size_t)SEQ * DM;       // 2,097,152 f: xi_raw, then delta
    float* bufC = bufB + (size_t)SEQ * DI;       // 2,097,152 f: z, then y (in-place)
    float* bufD = bufC + (size_t)SEQ * DI;       // 2,097,152 f: xi2
    float* hend = bufD + (size_t)SEQ * DI;       //   524,288 f: chunk h_end

    float* xn     = bufA;
    float* xi_raw = bufB;
    float* zy     = bufC;
    float* xi2    = bufD;
    float* dbc    = bufA;                        // reuse: xn dead after in-proj
    float* Pbuf   = bufA + (size_t)SEQ * 160;    // 524,288 f in bufA tail (after dbc)
    float* delta  = bufB;                        // reuse: xi_raw dead after conv

    // 1. LayerNorm
    ln_kernel<<<SEQ, 256, 0, stream>>>(x, ln_g, ln_b, xn);

    // 2a. xi_raw = xn @ Win[0:DI]^T   (2048 x 1024 x 512)
    gemm_kernel<0><<<dim3(SEQ / 64, DI / 64), 256, 0, stream>>>(
        xn, DM, Win, DM, SEQ, DI, DM, xi_raw, nullptr, nullptr, DI);
    // 2b. z = xn @ Win[DI:2*DI]^T     (2048 x 1024 x 512)
    gemm_kernel<0><<<dim3(SEQ / 64, DI / 64), 256, 0, stream>>>(
        xn, DM, Win + (size_t)DI * DM, DM, SEQ, DI, DM, zy, nullptr, nullptr, DI);

    // 3. conv + SiLU -> xi2
    conv_kernel<<<(SEQ * DI) / 256, 256, 0, stream>>>(xi_raw, conv_w, conv_b, xi2);

    // 4. dbc = xi2 @ Wx^T  (2048 x 160 x 1024)  [overwrites xn region]
    gemm_kernel<0><<<dim3(SEQ / 64, (160 + 63) / 64), 256, 0, stream>>>(
        xi2, DI, Wx, DI, SEQ, 160, DI, dbc, nullptr, nullptr, 160);

    // 5. delta = softplus(dbc[:, :32] @ Wdt^T + bdt)  (2048 x 1024 x 32)
    gemm_kernel<1><<<dim3(SEQ / 64, DI / 64), 256, 0, stream>>>(
        dbc, 160, Wdt, DR, SEQ, DI, DR, delta, bdt, nullptr, DI);

    // 6. chunked selective scan: A (local) -> carry -> B (emit y into zy)
    scan_passA<<<(DI * NCHUNK) / 4, 256, 0, stream>>>(delta, xi2, dbc, A_log, Pbuf, hend);
    scan_carry<<<DI / 4, 256, 0, stream>>>(Pbuf, hend);
    scan_passB<<<(DI * NCHUNK) / 4, 256, 0, stream>>>(delta, xi2, dbc, zy, A_log, Dp, Pbuf);

    // 7. out = y @ Wout^T + x  (2048 x 512 x 1024)
    gemm_kernel<2><<<dim3(SEQ / 64, DM / 64), 256, 0, stream>>>(
        zy, DI, Wout, DI, SEQ, DM, DI, out, nullptr, x, DM);
}

// Round 5
// 648.658 us; speedup vs baseline: 3.2547x; 1.3400x over previous
//
#include <hip/hip_runtime.h>
#include <hip/hip_bf16.h>
#include <cstddef>

#define SEQ 2048
#define DM  512
#define DI  1024   // d_inner
#define DR  32     // dt_rank
#define DS  64     // d_state
#define NCHUNK 8
#define CHUNK  256 // SEQ / NCHUNK

typedef __attribute__((ext_vector_type(4))) float f32x4;
typedef __attribute__((ext_vector_type(8))) short frag8;

// round-to-nearest-even f32 -> bf16 (finite inputs)
__device__ __forceinline__ short f2bf(float f) {
    unsigned u = __float_as_uint(f);
    unsigned r = (u + 0x7fffu + ((u >> 16) & 1u)) >> 16;
    return (short)r;
}

// ---------------- LayerNorm: one block (256 thr) per token ----------------
__global__ void ln_kernel(const float* __restrict__ x, const float* __restrict__ g,
                          const float* __restrict__ b, float* __restrict__ xn) {
    int l = blockIdx.x;
    int t = threadIdx.x;
    __shared__ float red[256];
    float v0 = x[l * DM + t];
    float v1 = x[l * DM + t + 256];
    red[t] = v0 + v1;
    __syncthreads();
    for (int o = 128; o > 0; o >>= 1) { if (t < o) red[t] += red[t + o]; __syncthreads(); }
    float mu = red[0] * (1.f / DM);
    __syncthreads();
    float c0 = v0 - mu, c1 = v1 - mu;
    red[t] = c0 * c0 + c1 * c1;
    __syncthreads();
    for (int o = 128; o > 0; o >>= 1) { if (t < o) red[t] += red[t + o]; __syncthreads(); }
    float rstd = rsqrtf(red[0] * (1.f / DM) + 1e-5f);
    xn[l * DM + t]       = c0 * rstd * g[t]       + b[t];
    xn[l * DM + t + 256] = c1 * rstd * g[t + 256] + b[t + 256];
}

// ---------------- MFMA GEMM: C[M,N] = A[M,K] * B[N,K]^T (fp32 in/out) -----
// A,B converted to bf16 in staging; fp32 accumulate via mfma_f32_16x16x32_bf16.
// Tile 128x64, BK=32, 256 thr = 4 waves, each wave 64x32 (4x2 tiles of 16x16).
// M fixed multiple of 128; N guarded. RES: add residual before store.
#define LDK 40   // padded row length (shorts): +16B pad -> <=2-way LDS conflicts
template <bool RES>
__global__ void gemm_mfma(const float* __restrict__ A, int lda,
                          const float* __restrict__ B, int ldb,
                          int N, int K,
                          float* __restrict__ out,
                          const float* __restrict__ res, int ldo) {
    __shared__ short As[128 * LDK];
    __shared__ short Bs[64 * LDK];
    int t = threadIdx.x;
    int lane = t & 63;
    int wv = t >> 6;
    int wm = (wv >> 1) * 64;   // wave m-offset in tile
    int wn = (wv & 1) * 32;    // wave n-offset in tile
    int m0 = blockIdx.x * 128, n0 = blockIdx.y * 64;

    f32x4 acc[4][2];
#pragma unroll
    for (int i = 0; i < 4; i++)
#pragma unroll
        for (int j = 0; j < 2; j++) acc[i][j] = (f32x4){0.f, 0.f, 0.f, 0.f};

    int lm = lane & 15;        // fragment row/col within 16
    int kq = (lane >> 4) * 8;  // fragment k-offset (quad*8)

    for (int k0 = 0; k0 < K; k0 += 32) {
        // stage A tile: 128x32 f32 -> bf16. 1024 chunks of 4; 4 per thread.
#pragma unroll
        for (int j = 0; j < 4; j++) {
            int c = t + j * 256;
            int m = c >> 3;            // 8 chunks per row
            int k = (c & 7) * 4;
            float4 v = *(const float4*)(A + (size_t)(m0 + m) * lda + k0 + k);
            short4 s = make_short4(f2bf(v.x), f2bf(v.y), f2bf(v.z), f2bf(v.w));
            *(short4*)(&As[m * LDK + k]) = s;
        }
        // stage B tile: 64x32 f32 -> bf16. 512 chunks; 2 per thread. N-guarded.
#pragma unroll
        for (int j = 0; j < 2; j++) {
            int c = t + j * 256;
            int n = c >> 3;
            int k = (c & 7) * 4;
            short4 s = make_short4(0, 0, 0, 0);
            int gn = n0 + n;
            if (gn < N) {
                float4 v = *(const float4*)(B + (size_t)gn * ldb + k0 + k);
                s = make_short4(f2bf(v.x), f2bf(v.y), f2bf(v.z), f2bf(v.w));
            }
            *(short4*)(&Bs[n * LDK + k]) = s;
        }
        __syncthreads();

        frag8 af[4], bfr[2];
#pragma unroll
        for (int mt = 0; mt < 4; mt++)
            af[mt] = *(const frag8*)(&As[(wm + mt * 16 + lm) * LDK + kq]);
#pragma unroll
        for (int nt = 0; nt < 2; nt++)
            bfr[nt] = *(const frag8*)(&Bs[(wn + nt * 16 + lm) * LDK + kq]);
#pragma unroll
        for (int mt = 0; mt < 4; mt++)
#pragma unroll
            for (int nt = 0; nt < 2; nt++)
                acc[mt][nt] = __builtin_amdgcn_mfma_f32_16x16x32_bf16(
                    af[mt], bfr[nt], acc[mt][nt], 0, 0, 0);
        __syncthreads();
    }

    // epilogue: C/D layout col=lane&15, row=(lane>>4)*4+reg
    int rbase = (lane >> 4) * 4;
#pragma unroll
    for (int mt = 0; mt < 4; mt++) {
#pragma unroll
        for (int nt = 0; nt < 2; nt++) {
            int n = n0 + wn + nt * 16 + lm;
            if (n < N) {
#pragma unroll
                for (int r = 0; r < 4; r++) {
                    int m = m0 + wm + mt * 16 + rbase + r;
                    float v = acc[mt][nt][r];
                    if (RES) v += res[(size_t)m * ldo + n];
                    out[(size_t)m * ldo + n] = v;
                }
            }
        }
    }
}

// ---------------- Vector GEMM (kept for dt-proj, K=32): softplus epilogue --
__global__ void gemm_dt(const float* __restrict__ A, int lda,
                        const float* __restrict__ B, int ldb,
                        int M, int N, int K,
                        float* __restrict__ out,
                        const float* __restrict__ ep_bias, int ldo) {
    __shared__ float As[16][65];
    __shared__ float Bs[16][65];
    int tid = threadIdx.x;
    int tx = tid & 15, ty = tid >> 4;
    int bm = blockIdx.x * 64, bn = blockIdx.y * 64;
    float acc[4][4] = {};
    int kk = tid & 15;
    int rr = tid >> 4;

    for (int k0 = 0; k0 < K; k0 += 16) {
#pragma unroll
        for (int i = 0; i < 4; i++) {
            int m = bm + rr + 16 * i;
            As[kk][rr + 16 * i] = (m < M) ? A[(size_t)m * lda + k0 + kk] : 0.f;
        }
#pragma unroll
        for (int i = 0; i < 4; i++) {
            int n = bn + rr + 16 * i;
            Bs[kk][rr + 16 * i] = (n < N) ? B[(size_t)n * ldb + k0 + kk] : 0.f;
        }
        __syncthreads();
#pragma unroll
        for (int k = 0; k < 16; k++) {
            float a[4], bb[4];
#pragma unroll
            for (int i = 0; i < 4; i++) a[i] = As[k][ty * 4 + i];
#pragma unroll
            for (int j = 0; j < 4; j++) bb[j] = Bs[k][tx * 4 + j];
#pragma unroll
            for (int i = 0; i < 4; i++)
#pragma unroll
                for (int j = 0; j < 4; j++)
                    acc[i][j] = fmaf(a[i], bb[j], acc[i][j]);
        }
        __syncthreads();
    }

#pragma unroll
    for (int i = 0; i < 4; i++) {
#pragma unroll
        for (int j = 0; j < 4; j++) {
            int m = bm + ty * 4 + i;
            int n = bn + tx * 4 + j;
            if (m < M && n < N) {
                float v = acc[i][j] + ep_bias[n];
                v = (v > 20.f) ? v : __logf(1.f + __expf(v));
                out[(size_t)m * ldo + n] = v;
            }
        }
    }
}

// ---------------- Causal depthwise conv (width 4) + bias + SiLU -----------
__global__ void conv_kernel(const float* __restrict__ xi_raw, const float* __restrict__ w,
                            const float* __restrict__ cb, float* __restrict__ xi2) {
    int idx = blockIdx.x * 256 + threadIdx.x;
    int e = idx & (DI - 1);
    int l = idx >> 10;
    float acc = cb[e];
#pragma unroll
    for (int j = 0; j < 4; j++) {
        int ls = l - 3 + j;
        if (ls >= 0) acc = fmaf(w[e * 4 + j], xi_raw[(size_t)ls * DI + e], acc);
    }
    float sig = 1.f / (1.f + __expf(-acc));
    xi2[idx] = acc * sig;
}

// ---------------- Chunked selective scan ----------------------------------
__global__ void scan_passA(const float* __restrict__ delta, const float* __restrict__ xi2,
                           const float* __restrict__ dbc, const float* __restrict__ A_log,
                           float* __restrict__ P, float* __restrict__ hend) {
    int wid = blockIdx.x * 4 + (threadIdx.x >> 6);
    int e = wid & (DI - 1);
    int c = wid >> 10;
    int n = threadIdx.x & 63;
    float Ae = -__expf(A_log[e * DS + n]);
    float h = 0.f, Pn = 1.f;
    int l0 = c * CHUNK;
    for (int l = l0; l < l0 + CHUNK; l++) {
        float d  = delta[l * DI + e];
        float xv = xi2[l * DI + e];
        float Bn = dbc[l * 160 + DR + n];
        float dA = __expf(d * Ae);
        h = fmaf(dA, h, d * xv * Bn);
        Pn *= dA;
    }
    int idx = (c * DI + e) * DS + n;
    P[idx] = Pn;
    hend[idx] = h;
}

__global__ void scan_carry(float* __restrict__ P, const float* __restrict__ hend) {
    int e = blockIdx.x * 4 + (threadIdx.x >> 6);
    int n = threadIdx.x & 63;
    float h = 0.f;
    for (int c = 0; c < NCHUNK; c++) {
        int idx = (c * DI + e) * DS + n;
        float p  = P[idx];
        float he = hend[idx];
        P[idx] = h;            // h_in for chunk c
        h = fmaf(p, h, he);
    }
}

__global__ void scan_passB(const float* __restrict__ delta, const float* __restrict__ xi2,
                           const float* __restrict__ dbc, float* __restrict__ zy,
                           const float* __restrict__ A_log, const float* __restrict__ Dp,
                           const float* __restrict__ hin) {
    int wid = blockIdx.x * 4 + (threadIdx.x >> 6);
    int e = wid & (DI - 1);
    int c = wid >> 10;
    int n = threadIdx.x & 63;
    float Ae = -__expf(A_log[e * DS + n]);
    float dp = Dp[e];
    float h = hin[(c * DI + e) * DS + n];
    int l0 = c * CHUNK;
    for (int l = l0; l < l0 + CHUNK; l++) {
        float d  = delta[l * DI + e];
        float xv = xi2[l * DI + e];
        float zv = zy[(size_t)l * DI + e];
        float Bn = dbc[l * 160 + DR + n];
        float Cn = dbc[l * 160 + DR + DS + n];
        float dA = __expf(d * Ae);
        h = fmaf(dA, h, d * xv * Bn);
        float p = h * Cn;
#pragma unroll
        for (int off = 32; off > 0; off >>= 1) p += __shfl_xor(p, off, 64);
        if (n == 0) {
            float yv = p + dp * xv;
            float sig = 1.f / (1.f + __expf(-zv));
            zy[(size_t)l * DI + e] = yv * (zv * sig);
        }
    }
}

extern "C" void kernel_launch(void* const* d_in, const int* in_sizes, int n_in,
                              void* d_out, int out_size, void* d_ws, size_t ws_size,
                              hipStream_t stream) {
    const float* x      = (const float*)d_in[0];
    const float* ln_g   = (const float*)d_in[1];
    const float* ln_b   = (const float*)d_in[2];
    const float* Win    = (const float*)d_in[3];
    const float* conv_w = (const float*)d_in[4];
    const float* conv_b = (const float*)d_in[5];
    const float* Wx     = (const float*)d_in[6];
    const float* Wdt    = (const float*)d_in[7];
    const float* bdt    = (const float*)d_in[8];
    const float* A_log  = (const float*)d_in[9];
    const float* Dp     = (const float*)d_in[10];
    const float* Wout   = (const float*)d_in[11];
    float* out = (float*)d_out;

    // Workspace layout identical to the passing R4 run (31.5 MB).
    float* ws   = (float*)d_ws;
    float* bufA = ws;                            // 1,048,576 f: xn, then dbc+P
    float* bufB = bufA + (size_t)SEQ * DM;       // 2,097,152 f: xi_raw, then delta
    float* bufC = bufB + (size_t)SEQ * DI;       // 2,097,152 f: z, then y (in-place)
    float* bufD = bufC + (size_t)SEQ * DI;       // 2,097,152 f: xi2
    float* hend = bufD + (size_t)SEQ * DI;       //   524,288 f

    float* xn     = bufA;
    float* xi_raw = bufB;
    float* zy     = bufC;
    float* xi2    = bufD;
    float* dbc    = bufA;                        // reuse: xn dead after in-proj
    float* Pbuf   = bufA + (size_t)SEQ * 160;    // bufA tail after dbc
    float* delta  = bufB;                        // reuse: xi_raw dead after conv

    // 1. LayerNorm
    ln_kernel<<<SEQ, 256, 0, stream>>>(x, ln_g, ln_b, xn);

    // 2a. xi_raw = xn @ Win[0:DI]^T   (MFMA, 2048 x 1024 x 512)
    gemm_mfma<false><<<dim3(SEQ / 128, DI / 64), 256, 0, stream>>>(
        xn, DM, Win, DM, DI, DM, xi_raw, nullptr, DI);
    // 2b. z = xn @ Win[DI:2*DI]^T     (MFMA, 2048 x 1024 x 512)
    gemm_mfma<false><<<dim3(SEQ / 128, DI / 64), 256, 0, stream>>>(
        xn, DM, Win + (size_t)DI * DM, DM, DI, DM, zy, nullptr, DI);

    // 3. conv + SiLU -> xi2
    conv_kernel<<<(SEQ * DI) / 256, 256, 0, stream>>>(xi_raw, conv_w, conv_b, xi2);

    // 4. dbc = xi2 @ Wx^T  (MFMA, 2048 x 160 x 1024, N-guarded)
    gemm_mfma<false><<<dim3(SEQ / 128, (160 + 63) / 64), 256, 0, stream>>>(
        xi2, DI, Wx, DI, 160, DI, dbc, nullptr, 160);

    // 5. delta = softplus(dbc[:, :32] @ Wdt^T + bdt)  (vector, 2048 x 1024 x 32)
    gemm_dt<<<dim3(SEQ / 64, DI / 64), 256, 0, stream>>>(
        dbc, 160, Wdt, DR, SEQ, DI, DR, delta, bdt, DI);

    // 6. chunked selective scan: A (local) -> carry -> B (emit y into zy)
    scan_passA<<<(DI * NCHUNK) / 4, 256, 0, stream>>>(delta, xi2, dbc, A_log, Pbuf, hend);
    scan_carry<<<DI / 4, 256, 0, stream>>>(Pbuf, hend);
    scan_passB<<<(DI * NCHUNK) / 4, 256, 0, stream>>>(delta, xi2, dbc, zy, A_log, Dp, Pbuf);

    // 7. out = y @ Wout^T + x  (MFMA, 2048 x 512 x 1024, fused residual)
    gemm_mfma<true><<<dim3(SEQ / 128, DM / 64), 256, 0, stream>>>(
        zy, DI, Wout, DI, DM, DI, out, x, DM);
}

// Round 7
// 574.962 us; speedup vs baseline: 3.6719x; 1.1282x over previous
//
#include <hip/hip_runtime.h>
#include <hip/hip_bf16.h>
#include <cstddef>

#define SEQ 2048
#define DM  512
#define DI  1024   // d_inner
#define DR  32     // dt_rank
#define DS  64     // d_state
#define NCHUNK 8
#define CHUNK  256 // SEQ / NCHUNK

typedef __attribute__((ext_vector_type(4))) float f32x4;
typedef __attribute__((ext_vector_type(8))) short frag8;

// round-to-nearest-even f32 -> bf16 (finite inputs)
__device__ __forceinline__ short f2bf(float f) {
    unsigned u = __float_as_uint(f);
    unsigned r = (u + 0x7fffu + ((u >> 16) & 1u)) >> 16;
    return (short)r;
}

// p + dpp_permute(p) with compile-time DPP control (update_dpp needs an ICE)
template <int CTRL>
__device__ __forceinline__ float dppadd(float p) {
    return p + __int_as_float(
        __builtin_amdgcn_update_dpp(0, __float_as_int(p), CTRL, 0xF, 0xF, true));
}

// ---------------- LayerNorm: one block (256 thr) per token ----------------
__global__ void ln_kernel(const float* __restrict__ x, const float* __restrict__ g,
                          const float* __restrict__ b, float* __restrict__ xn) {
    int l = blockIdx.x;
    int t = threadIdx.x;
    __shared__ float red[256];
    float v0 = x[l * DM + t];
    float v1 = x[l * DM + t + 256];
    red[t] = v0 + v1;
    __syncthreads();
    for (int o = 128; o > 0; o >>= 1) { if (t < o) red[t] += red[t + o]; __syncthreads(); }
    float mu = red[0] * (1.f / DM);
    __syncthreads();
    float c0 = v0 - mu, c1 = v1 - mu;
    red[t] = c0 * c0 + c1 * c1;
    __syncthreads();
    for (int o = 128; o > 0; o >>= 1) { if (t < o) red[t] += red[t + o]; __syncthreads(); }
    float rstd = rsqrtf(red[0] * (1.f / DM) + 1e-5f);
    xn[l * DM + t]       = c0 * rstd * g[t]       + b[t];
    xn[l * DM + t + 256] = c1 * rstd * g[t + 256] + b[t + 256];
}

// ---------------- MFMA GEMM: C[M,N] = A[M,K] * B[N,K]^T (fp32 in/out) -----
// A,B converted to bf16 in staging; fp32 accumulate via mfma_f32_16x16x32_bf16.
// Tile 128x64, BK=32, 256 thr = 4 waves, each wave 64x32 (4x2 tiles of 16x16).
// M fixed multiple of 128; N guarded. EPI: 0=store, 1=silu(v), 2=v+residual.
#define LDK 40   // padded row length (shorts): +16B pad -> <=2-way LDS conflicts
template <int EPI>
__global__ void gemm_mfma(const float* __restrict__ A, int lda,
                          const float* __restrict__ B, int ldb,
                          int N, int K,
                          float* __restrict__ out,
                          const float* __restrict__ res, int ldo) {
    __shared__ short As[128 * LDK];
    __shared__ short Bs[64 * LDK];
    int t = threadIdx.x;
    int lane = t & 63;
    int wv = t >> 6;
    int wm = (wv >> 1) * 64;   // wave m-offset in tile
    int wn = (wv & 1) * 32;    // wave n-offset in tile
    int m0 = blockIdx.x * 128, n0 = blockIdx.y * 64;

    f32x4 acc[4][2];
#pragma unroll
    for (int i = 0; i < 4; i++)
#pragma unroll
        for (int j = 0; j < 2; j++) acc[i][j] = (f32x4){0.f, 0.f, 0.f, 0.f};

    int lm = lane & 15;        // fragment row/col within 16
    int kq = (lane >> 4) * 8;  // fragment k-offset (quad*8)

    for (int k0 = 0; k0 < K; k0 += 32) {
        // stage A tile: 128x32 f32 -> bf16. 1024 chunks of 4; 4 per thread.
#pragma unroll
        for (int j = 0; j < 4; j++) {
            int c = t + j * 256;
            int m = c >> 3;            // 8 chunks per row
            int k = (c & 7) * 4;
            float4 v = *(const float4*)(A + (size_t)(m0 + m) * lda + k0 + k);
            short4 s = make_short4(f2bf(v.x), f2bf(v.y), f2bf(v.z), f2bf(v.w));
            *(short4*)(&As[m * LDK + k]) = s;
        }
        // stage B tile: 64x32 f32 -> bf16. 512 chunks; 2 per thread. N-guarded.
#pragma unroll
        for (int j = 0; j < 2; j++) {
            int c = t + j * 256;
            int n = c >> 3;
            int k = (c & 7) * 4;
            short4 s = make_short4(0, 0, 0, 0);
            int gn = n0 + n;
            if (gn < N) {
                float4 v = *(const float4*)(B + (size_t)gn * ldb + k0 + k);
                s = make_short4(f2bf(v.x), f2bf(v.y), f2bf(v.z), f2bf(v.w));
            }
            *(short4*)(&Bs[n * LDK + k]) = s;
        }
        __syncthreads();

        frag8 af[4], bfr[2];
#pragma unroll
        for (int mt = 0; mt < 4; mt++)
            af[mt] = *(const frag8*)(&As[(wm + mt * 16 + lm) * LDK + kq]);
#pragma unroll
        for (int nt = 0; nt < 2; nt++)
            bfr[nt] = *(const frag8*)(&Bs[(wn + nt * 16 + lm) * LDK + kq]);
#pragma unroll
        for (int mt = 0; mt < 4; mt++)
#pragma unroll
            for (int nt = 0; nt < 2; nt++)
                acc[mt][nt] = __builtin_amdgcn_mfma_f32_16x16x32_bf16(
                    af[mt], bfr[nt], acc[mt][nt], 0, 0, 0);
        __syncthreads();
    }

    // epilogue: C/D layout col=lane&15, row=(lane>>4)*4+reg
    int rbase = (lane >> 4) * 4;
#pragma unroll
    for (int mt = 0; mt < 4; mt++) {
#pragma unroll
        for (int nt = 0; nt < 2; nt++) {
            int n = n0 + wn + nt * 16 + lm;
            if (n < N) {
#pragma unroll
                for (int r = 0; r < 4; r++) {
                    int m = m0 + wm + mt * 16 + rbase + r;
                    float v = acc[mt][nt][r];
                    if (EPI == 1) {
                        float sig = 1.f / (1.f + __expf(-v));
                        v = v * sig;
                    } else if (EPI == 2) {
                        v += res[(size_t)m * ldo + n];
                    }
                    out[(size_t)m * ldo + n] = v;
                }
            }
        }
    }
}

// ---------------- Vector GEMM (kept for dt-proj, K=32): softplus epilogue --
__global__ void gemm_dt(const float* __restrict__ A, int lda,
                        const float* __restrict__ B, int ldb,
                        int M, int N, int K,
                        float* __restrict__ out,
                        const float* __restrict__ ep_bias, int ldo) {
    __shared__ float As[16][65];
    __shared__ float Bs[16][65];
    int tid = threadIdx.x;
    int tx = tid & 15, ty = tid >> 4;
    int bm = blockIdx.x * 64, bn = blockIdx.y * 64;
    float acc[4][4] = {};
    int kk = tid & 15;
    int rr = tid >> 4;

    for (int k0 = 0; k0 < K; k0 += 16) {
#pragma unroll
        for (int i = 0; i < 4; i++) {
            int m = bm + rr + 16 * i;
            As[kk][rr + 16 * i] = (m < M) ? A[(size_t)m * lda + k0 + kk] : 0.f;
        }
#pragma unroll
        for (int i = 0; i < 4; i++) {
            int n = bn + rr + 16 * i;
            Bs[kk][rr + 16 * i] = (n < N) ? B[(size_t)n * ldb + k0 + kk] : 0.f;
        }
        __syncthreads();
#pragma unroll
        for (int k = 0; k < 16; k++) {
            float a[4], bb[4];
#pragma unroll
            for (int i = 0; i < 4; i++) a[i] = As[k][ty * 4 + i];
#pragma unroll
            for (int j = 0; j < 4; j++) bb[j] = Bs[k][tx * 4 + j];
#pragma unroll
            for (int i = 0; i < 4; i++)
#pragma unroll
                for (int j = 0; j < 4; j++)
                    acc[i][j] = fmaf(a[i], bb[j], acc[i][j]);
        }
        __syncthreads();
    }

#pragma unroll
    for (int i = 0; i < 4; i++) {
#pragma unroll
        for (int j = 0; j < 4; j++) {
            int m = bm + ty * 4 + i;
            int n = bn + tx * 4 + j;
            if (m < M && n < N) {
                float v = acc[i][j] + ep_bias[n];
                v = (v > 20.f) ? v : __logf(1.f + __expf(v));
                out[(size_t)m * ldo + n] = v;
            }
        }
    }
}

// ---------------- Causal depthwise conv (width 4) + bias + SiLU -----------
__global__ void conv_kernel(const float* __restrict__ xi_raw, const float* __restrict__ w,
                            const float* __restrict__ cb, float* __restrict__ xi2) {
    int idx = blockIdx.x * 256 + threadIdx.x;
    int e = idx & (DI - 1);
    int l = idx >> 10;
    float acc = cb[e];
#pragma unroll
    for (int j = 0; j < 4; j++) {
        int ls = l - 3 + j;
        if (ls >= 0) acc = fmaf(w[e * 4 + j], xi_raw[(size_t)ls * DI + e], acc);
    }
    float sig = 1.f / (1.f + __expf(-acc));
    xi2[idx] = acc * sig;
}

// ---------------- Chunked selective scan ----------------------------------
// Pass A: local scan (h_in = 0). P = prod(dA) = exp(Ae * sum(d)) computed once.
__global__ void scan_passA(const float* __restrict__ delta, const float* __restrict__ xi2,
                           const float* __restrict__ dbc, const float* __restrict__ A_log,
                           float* __restrict__ P, float* __restrict__ hend) {
    int wid = blockIdx.x * 4 + (threadIdx.x >> 6);
    int e = wid & (DI - 1);
    int c = wid >> 10;
    int n = threadIdx.x & 63;
    float Ae = -__expf(A_log[e * DS + n]);
    float h = 0.f, sum_d = 0.f;
    int l0 = c * CHUNK;
#pragma unroll 4
    for (int l = l0; l < l0 + CHUNK; l++) {
        float d  = delta[l * DI + e];
        float xv = xi2[l * DI + e];
        float Bn = dbc[l * 160 + DR + n];
        float dA = __expf(d * Ae);
        h = fmaf(dA, h, (d * xv) * Bn);
        sum_d += d;
    }
    int idx = (c * DI + e) * DS + n;
    P[idx] = __expf(Ae * sum_d);
    hend[idx] = h;
}

__global__ void scan_carry(float* __restrict__ P, const float* __restrict__ hend) {
    int e = blockIdx.x * 4 + (threadIdx.x >> 6);
    int n = threadIdx.x & 63;
    float h = 0.f;
    for (int c = 0; c < NCHUNK; c++) {
        int idx = (c * DI + e) * DS + n;
        float p  = P[idx];
        float he = hend[idx];
        P[idx] = h;            // h_in for chunk c
        h = fmaf(p, h, he);
    }
}

// Pass B: re-scan from exact h_in. Reduction via DPP (16-lane) + readlane.
// zy holds silu(z) on input (from GEMM epilogue), overwritten in-place with y.
__global__ void scan_passB(const float* __restrict__ delta, const float* __restrict__ xi2,
                           const float* __restrict__ dbc, float* __restrict__ zy,
                           const float* __restrict__ A_log, const float* __restrict__ Dp,
                           const float* __restrict__ hin) {
    int wid = blockIdx.x * 4 + (threadIdx.x >> 6);
    int e = wid & (DI - 1);
    int c = wid >> 10;
    int n = threadIdx.x & 63;
    float Ae = -__expf(A_log[e * DS + n]);
    float dp = Dp[e];
    float h = hin[(c * DI + e) * DS + n];
    int l0 = c * CHUNK;
#pragma unroll 2
    for (int l = l0; l < l0 + CHUNK; l++) {
        float d  = delta[l * DI + e];
        float xv = xi2[l * DI + e];
        float sz = zy[(size_t)l * DI + e];
        float Bn = dbc[l * 160 + DR + n];
        float Cn = dbc[l * 160 + DR + DS + n];
        float dA = __expf(d * Ae);
        h = fmaf(dA, h, (d * xv) * Bn);
        float p = h * Cn;
        // 16-lane butterfly via DPP: quad_perm(1,0,3,2)=0xB1, quad_perm(2,3,0,1)=0x4E,
        // row_half_mirror=0x141, row_mirror=0x140
        p = dppadd<0xB1>(p);
        p = dppadd<0x4E>(p);
        p = dppadd<0x141>(p);
        p = dppadd<0x140>(p);
        // cross-row: rows 1..3 sums -> combine for lane 0
        float s1 = __int_as_float(__builtin_amdgcn_readlane(__float_as_int(p), 16));
        float s2 = __int_as_float(__builtin_amdgcn_readlane(__float_as_int(p), 32));
        float s3 = __int_as_float(__builtin_amdgcn_readlane(__float_as_int(p), 48));
        if (n == 0) {
            float yv = p + s1 + s2 + s3 + dp * xv;
            zy[(size_t)l * DI + e] = yv * sz;
        }
    }
}

extern "C" void kernel_launch(void* const* d_in, const int* in_sizes, int n_in,
                              void* d_out, int out_size, void* d_ws, size_t ws_size,
                              hipStream_t stream) {
    const float* x      = (const float*)d_in[0];
    const float* ln_g   = (const float*)d_in[1];
    const float* ln_b   = (const float*)d_in[2];
    const float* Win    = (const float*)d_in[3];
    const float* conv_w = (const float*)d_in[4];
    const float* conv_b = (const float*)d_in[5];
    const float* Wx     = (const float*)d_in[6];
    const float* Wdt    = (const float*)d_in[7];
    const float* bdt    = (const float*)d_in[8];
    const float* A_log  = (const float*)d_in[9];
    const float* Dp     = (const float*)d_in[10];
    const float* Wout   = (const float*)d_in[11];
    float* out = (float*)d_out;

    // Workspace layout identical to the passing R4/R5 runs (31.5 MB).
    float* ws   = (float*)d_ws;
    float* bufA = ws;                            // 1,048,576 f: xn, then dbc+P
    float* bufB = bufA + (size_t)SEQ * DM;       // 2,097,152 f: xi_raw, then delta
    float* bufC = bufB + (size_t)SEQ * DI;       // 2,097,152 f: silu(z), then y
    float* bufD = bufC + (size_t)SEQ * DI;       // 2,097,152 f: xi2
    float* hend = bufD + (size_t)SEQ * DI;       //   524,288 f

    float* xn     = bufA;
    float* xi_raw = bufB;
    float* zy     = bufC;
    float* xi2    = bufD;
    float* dbc    = bufA;                        // reuse: xn dead after in-proj
    float* Pbuf   = bufA + (size_t)SEQ * 160;    // bufA tail after dbc
    float* delta  = bufB;                        // reuse: xi_raw dead after conv

    // 1. LayerNorm
    ln_kernel<<<SEQ, 256, 0, stream>>>(x, ln_g, ln_b, xn);

    // 2a. xi_raw = xn @ Win[0:DI]^T   (MFMA, 2048 x 1024 x 512)
    gemm_mfma<0><<<dim3(SEQ / 128, DI / 64), 256, 0, stream>>>(
        xn, DM, Win, DM, DI, DM, xi_raw, nullptr, DI);
    // 2b. zy = silu(xn @ Win[DI:2*DI]^T)  (MFMA + silu epilogue)
    gemm_mfma<1><<<dim3(SEQ / 128, DI / 64), 256, 0, stream>>>(
        xn, DM, Win + (size_t)DI * DM, DM, DI, DM, zy, nullptr, DI);

    // 3. conv + SiLU -> xi2
    conv_kernel<<<(SEQ * DI) / 256, 256, 0, stream>>>(xi_raw, conv_w, conv_b, xi2);

    // 4. dbc = xi2 @ Wx^T  (MFMA, 2048 x 160 x 1024, N-guarded)
    gemm_mfma<0><<<dim3(SEQ / 128, (160 + 63) / 64), 256, 0, stream>>>(
        xi2, DI, Wx, DI, 160, DI, dbc, nullptr, 160);

    // 5. delta = softplus(dbc[:, :32] @ Wdt^T + bdt)  (vector, 2048 x 1024 x 32)
    gemm_dt<<<dim3(SEQ / 64, DI / 64), 256, 0, stream>>>(
        dbc, 160, Wdt, DR, SEQ, DI, DR, delta, bdt, DI);

    // 6. chunked selective scan: A (local) -> carry -> B (emit y into zy)
    scan_passA<<<(DI * NCHUNK) / 4, 256, 0, stream>>>(delta, xi2, dbc, A_log, Pbuf, hend);
    scan_carry<<<DI / 4, 256, 0, stream>>>(Pbuf, hend);
    scan_passB<<<(DI * NCHUNK) / 4, 256, 0, stream>>>(delta, xi2, dbc, zy, A_log, Dp, Pbuf);

    // 7. out = y @ Wout^T + x  (MFMA, 2048 x 512 x 1024, fused residual)
    gemm_mfma<2><<<dim3(SEQ / 128, DM / 64), 256, 0, stream>>>(
        zy, DI, Wout, DI, DM, DI, out, x, DM);
}